// Round 1
// baseline (424.890 us; speedup 1.0000x reference)
//
#include <hip/hip_runtime.h>
#include <math.h>

// Problem constants: x (8, 96, 256, 256) fp32; K=3, pad=1, stride=1.
//   pooled = mean(x, axis=(2,3))            (8,96)
//   hid    = relu(pooled @ w1.T + b1)       (8,12)
//   kw     = softmax(hid @ w2.T + b2)       (8,9)
//   out[b,c,i,j] = sum_{di,dj} kw[b,di*3+dj] * x_pad[b,c,i+di-1,j+dj-1]

#define NB 8
#define NC 96
#define HH 256
#define WW 256
#define PLANE (HH * WW)          // 65536 floats per (b,c) plane
#define NPLANES (NB * NC)        // 768

// ---------------- Kernel 1: global average pool ----------------
// One block per (b,c) plane. 256 threads, each sums 64 float4 (strided, coalesced).
__global__ __launch_bounds__(256) void pool_kernel(const float* __restrict__ x,
                                                   float* __restrict__ pooled) {
    const int plane = blockIdx.x;
    const int tid = threadIdx.x;
    const float4* xp = (const float4*)x + (size_t)plane * (PLANE / 4);
    float s = 0.f;
#pragma unroll 8
    for (int k = 0; k < 64; ++k) {
        float4 v = xp[k * 256 + tid];
        s += v.x + v.y + v.z + v.w;
    }
    // wave-64 shuffle reduction
#pragma unroll
    for (int off = 32; off > 0; off >>= 1) s += __shfl_down(s, off);
    __shared__ float ws[4];
    if ((tid & 63) == 0) ws[tid >> 6] = s;
    __syncthreads();
    if (tid == 0)
        pooled[plane] = (ws[0] + ws[1] + ws[2] + ws[3]) * (1.0f / (float)PLANE);
}

// ---------------- Kernel 2: tiny attention MLP + softmax ----------------
// One block per batch. Cost is negligible; clarity over speed.
__global__ __launch_bounds__(128) void attn_kernel(const float* __restrict__ pooled,
                                                   const float* __restrict__ w1,
                                                   const float* __restrict__ b1,
                                                   const float* __restrict__ w2,
                                                   const float* __restrict__ b2,
                                                   float* __restrict__ kw) {
    const int b = blockIdx.x;
    const int tid = threadIdx.x;
    __shared__ float p[NC];
    __shared__ float hid[12];
    __shared__ float logit[9];
    if (tid < NC) p[tid] = pooled[b * NC + tid];
    __syncthreads();
    if (tid < 12) {
        float a = b1[tid];
#pragma unroll
        for (int c = 0; c < NC; ++c) a = fmaf(p[c], w1[tid * NC + c], a);
        hid[tid] = a > 0.f ? a : 0.f;
    }
    __syncthreads();
    if (tid < 9) {
        float a = b2[tid];
#pragma unroll
        for (int j = 0; j < 12; ++j) a = fmaf(hid[j], w2[tid * 12 + j], a);
        logit[tid] = a;
    }
    __syncthreads();
    if (tid == 0) {
        float m = logit[0];
#pragma unroll
        for (int q = 1; q < 9; ++q) m = fmaxf(m, logit[q]);
        float e[9], s = 0.f;
#pragma unroll
        for (int q = 0; q < 9; ++q) { e[q] = __expf(logit[q] - m); s += e[q]; }
        float inv = 1.f / s;
#pragma unroll
        for (int q = 0; q < 9; ++q) kw[b * 9 + q] = e[q] * inv;
    }
}

// ---------------- Kernel 3: dynamic 3x3 depthwise conv ----------------
__device__ __forceinline__ void accum_row(const float* __restrict__ row, int t,
                                          float w0, float w1, float w2, float4& o) {
    const int jc = t << 2;
    float4 cc = *(const float4*)(row + jc);
    float lm = (t > 0) ? row[jc - 1] : 0.f;           // left halo (zero pad at j=0)
    float rp = (t < (WW / 4 - 1)) ? row[jc + 4] : 0.f; // right halo
    o.x = fmaf(w0, lm,   fmaf(w1, cc.x, fmaf(w2, cc.y, o.x)));
    o.y = fmaf(w0, cc.x, fmaf(w1, cc.y, fmaf(w2, cc.z, o.y)));
    o.z = fmaf(w0, cc.y, fmaf(w1, cc.z, fmaf(w2, cc.w, o.z)));
    o.w = fmaf(w0, cc.z, fmaf(w1, cc.w, fmaf(w2, rp,   o.w)));
}

// grid: (64 blocks/plane, 96 channels, 8 batches); 256 threads = 4 rows x 64 float4/row.
__global__ __launch_bounds__(256) void conv_kernel(const float* __restrict__ x,
                                                   const float* __restrict__ kw9,
                                                   float* __restrict__ out) {
    const int q = blockIdx.x * 256 + threadIdx.x;  // 0..16383 within plane
    const int i = q >> 6;                          // output row
    const int t = q & 63;                          // float4 column index

    const size_t base = ((size_t)(blockIdx.z * NC + blockIdx.y)) * PLANE;
    const float* xpl = x + base;

    float w[9];
#pragma unroll
    for (int p = 0; p < 9; ++p) w[p] = kw9[blockIdx.z * 9 + p];  // block-uniform

    float4 o = {0.f, 0.f, 0.f, 0.f};
    if (i > 0)        accum_row(xpl + (size_t)(i - 1) * WW, t, w[0], w[1], w[2], o);
                      accum_row(xpl + (size_t)i * WW,       t, w[3], w[4], w[5], o);
    if (i < HH - 1)   accum_row(xpl + (size_t)(i + 1) * WW, t, w[6], w[7], w[8], o);

    *(float4*)(out + base + (size_t)i * WW + (t << 2)) = o;
}

extern "C" void kernel_launch(void* const* d_in, const int* in_sizes, int n_in,
                              void* d_out, int out_size, void* d_ws, size_t ws_size,
                              hipStream_t stream) {
    const float* x  = (const float*)d_in[0];
    const float* w1 = (const float*)d_in[1];
    const float* b1 = (const float*)d_in[2];
    const float* w2 = (const float*)d_in[3];
    const float* b2 = (const float*)d_in[4];
    float* out = (float*)d_out;

    float* pooled = (float*)d_ws;              // 768 floats
    float* kw     = pooled + NPLANES;          // 72 floats

    pool_kernel<<<NPLANES, 256, 0, stream>>>(x, pooled);
    attn_kernel<<<NB, 128, 0, stream>>>(pooled, w1, b1, w2, b2, kw);
    dim3 grid(PLANE / (4 * 256), NC, NB);      // (64, 96, 8)
    conv_kernel<<<grid, 256, 0, stream>>>(x, kw, out);
}

// Round 3
// 374.167 us; speedup vs baseline: 1.1356x; 1.1356x over previous
//
#include <hip/hip_runtime.h>
#include <math.h>

// x (8, 96, 256, 256) fp32; K=3, pad=1, stride=1.
//   pooled = mean(x, axis=(2,3)); hid = relu(pooled@w1.T+b1);
//   kw = softmax(hid@w2.T+b2)  (8,9)
//   out[b,c,i,j] = sum_{di,dj} kw[b,di*3+dj] * x_pad[b,c,i+di-1,j+dj-1]

#define NB 8
#define NC 96
#define HH 256
#define WW 256
#define PLANE (HH * WW)
#define NPLANES (NB * NC)

typedef float vfloat4 __attribute__((ext_vector_type(4)));  // clang-native, NT-store OK

// ---------------- Kernel 1: global average pool ----------------
__global__ __launch_bounds__(256) void pool_kernel(const float* __restrict__ x,
                                                   float* __restrict__ pooled) {
    const int plane = blockIdx.x;
    const int tid = threadIdx.x;
    const vfloat4* xp = (const vfloat4*)x + (size_t)plane * (PLANE / 4);
    float s = 0.f;
#pragma unroll 8
    for (int k = 0; k < 64; ++k) {
        vfloat4 v = xp[k * 256 + tid];
        s += v.x + v.y + v.z + v.w;
    }
#pragma unroll
    for (int off = 32; off > 0; off >>= 1) s += __shfl_down(s, off);
    __shared__ float ws[4];
    if ((tid & 63) == 0) ws[tid >> 6] = s;
    __syncthreads();
    if (tid == 0)
        pooled[plane] = (ws[0] + ws[1] + ws[2] + ws[3]) * (1.0f / (float)PLANE);
}

// ---------------- Kernel 2: tiny attention MLP + softmax ----------------
__global__ __launch_bounds__(128) void attn_kernel(const float* __restrict__ pooled,
                                                   const float* __restrict__ w1,
                                                   const float* __restrict__ b1,
                                                   const float* __restrict__ w2,
                                                   const float* __restrict__ b2,
                                                   float* __restrict__ kw) {
    const int b = blockIdx.x;
    const int tid = threadIdx.x;
    __shared__ float p[NC];
    __shared__ float hid[12];
    __shared__ float logit[9];
    if (tid < NC) p[tid] = pooled[b * NC + tid];
    __syncthreads();
    if (tid < 12) {
        float a = b1[tid];
#pragma unroll
        for (int c = 0; c < NC; ++c) a = fmaf(p[c], w1[tid * NC + c], a);
        hid[tid] = a > 0.f ? a : 0.f;
    }
    __syncthreads();
    if (tid < 9) {
        float a = b2[tid];
#pragma unroll
        for (int j = 0; j < 12; ++j) a = fmaf(hid[j], w2[tid * 12 + j], a);
        logit[tid] = a;
    }
    __syncthreads();
    if (tid == 0) {
        float m = logit[0];
#pragma unroll
        for (int q = 1; q < 9; ++q) m = fmaxf(m, logit[q]);
        float e[9], s = 0.f;
#pragma unroll
        for (int q = 0; q < 9; ++q) { e[q] = __expf(logit[q] - m); s += e[q]; }
        float inv = 1.f / s;
#pragma unroll
        for (int q = 0; q < 9; ++q) kw[b * 9 + q] = e[q] * inv;
    }
}

// ---------------- Kernel 3: rolling-row dynamic 3x3 depthwise conv ----------------
// One wave (64 lanes) owns a full 256-float row (lane = float4 column), walks a
// 32-row strip keeping 3 rows in registers. Horizontal halos via shuffles.
struct Row {
    vfloat4 v;
    float hl, hr;  // col jc-1 (from lane-1) and col jc+4 (from lane+1)
};

__device__ __forceinline__ Row load_row(const float* __restrict__ rowp, int lane) {
    Row r;
    r.v = *(const vfloat4*)(rowp + (lane << 2));
    float up = __shfl_up(r.v.w, 1);
    float dn = __shfl_down(r.v.x, 1);
    r.hl = (lane == 0) ? 0.f : up;     // zero pad at j = -1
    r.hr = (lane == 63) ? 0.f : dn;    // zero pad at j = 256
    return r;
}

__device__ __forceinline__ Row zero_row() {
    Row r; r.v = (vfloat4){0.f, 0.f, 0.f, 0.f}; r.hl = 0.f; r.hr = 0.f; return r;
}

__device__ __forceinline__ void row_fma(const Row& r, float wl, float wc, float wr,
                                        vfloat4& o) {
    o.x = fmaf(wl, r.hl,  fmaf(wc, r.v.x, fmaf(wr, r.v.y, o.x)));
    o.y = fmaf(wl, r.v.x, fmaf(wc, r.v.y, fmaf(wr, r.v.z, o.y)));
    o.z = fmaf(wl, r.v.y, fmaf(wc, r.v.z, fmaf(wr, r.v.w, o.z)));
    o.w = fmaf(wl, r.v.z, fmaf(wc, r.v.w, fmaf(wr, r.hr,  o.w)));
}

// grid: (2 strips-of-4-waves, 96 channels, 8 batches); block 256 = 4 waves,
// each wave a 32-row strip. Per wave: 34 rows loaded / 32 produced (1.06x).
__global__ __launch_bounds__(256) void conv_kernel(const float* __restrict__ x,
                                                   const float* __restrict__ kw9,
                                                   float* __restrict__ out) {
    const int lane = threadIdx.x & 63;
    const int strip = (blockIdx.x << 2) + (threadIdx.x >> 6);  // 0..7
    const int rs = strip << 5;                                 // first output row

    const size_t base = ((size_t)(blockIdx.z * NC + blockIdx.y)) * PLANE;
    const float* xpl = x + base;
    float* opl = out + base;

    float w[9];
#pragma unroll
    for (int p = 0; p < 9; ++p) w[p] = kw9[blockIdx.z * 9 + p];  // block-uniform

    Row a = (rs == 0) ? zero_row() : load_row(xpl + (size_t)(rs - 1) * WW, lane);
    Row b = load_row(xpl + (size_t)rs * WW, lane);

#pragma unroll 4
    for (int i = rs; i < rs + 32; ++i) {
        Row c = (i + 1 < HH) ? load_row(xpl + (size_t)(i + 1) * WW, lane)
                             : zero_row();
        vfloat4 o = (vfloat4){0.f, 0.f, 0.f, 0.f};
        row_fma(a, w[0], w[1], w[2], o);
        row_fma(b, w[3], w[4], w[5], o);
        row_fma(c, w[6], w[7], w[8], o);
        __builtin_nontemporal_store(o, (vfloat4*)(opl + (size_t)i * WW + (lane << 2)));
        a = b; b = c;
    }
}

extern "C" void kernel_launch(void* const* d_in, const int* in_sizes, int n_in,
                              void* d_out, int out_size, void* d_ws, size_t ws_size,
                              hipStream_t stream) {
    const float* x  = (const float*)d_in[0];
    const float* w1 = (const float*)d_in[1];
    const float* b1 = (const float*)d_in[2];
    const float* w2 = (const float*)d_in[3];
    const float* b2 = (const float*)d_in[4];
    float* out = (float*)d_out;

    float* pooled = (float*)d_ws;       // 768 floats
    float* kw     = pooled + NPLANES;   // 72 floats

    pool_kernel<<<NPLANES, 256, 0, stream>>>(x, pooled);
    attn_kernel<<<NB, 128, 0, stream>>>(pooled, w1, b1, w2, b2, kw);
    dim3 grid(2, NC, NB);               // 1536 blocks, 6/CU, 24 waves/CU
    conv_kernel<<<grid, 256, 0, stream>>>(x, kw, out);
}